// Round 5
// baseline (5091.338 us; speedup 1.0000x reference)
//
#include <hip/hip_runtime.h>

#define N_IMG 128
#define BINS 128
#define HW_ELEMS (1 << 20)                       // 1024*1024 per image
#define NBLOCKS 1024                             // 4 blocks/CU x 256 CUs (co-resident)
#define CHUNK_ELEMS 4096                         // 16 KB chunk staged in LDS
#define CHUNK_V4 (CHUNK_ELEMS / 4)               // 1024 float4
#define CHUNKS_PER_IMG (HW_ELEMS / CHUNK_ELEMS)  // 256
#define IMGS_PER_SLOT (NBLOCKS / CHUNKS_PER_IMG) // 4
#define IMGS_PER_ROUND (2 * IMGS_PER_SLOT)       // 8
#define ROUNDS (N_IMG / IMGS_PER_ROUND)          // 16
#define NCOPY 8                                  // privatized LDS hist copies (32 lanes each)
#define HPAD 132                                 // 132 % 32 = 4 -> phase-shifted banks

typedef float f32x4 __attribute__((ext_vector_type(4)));

// One persistent fused kernel: per 16KB chunk -> {hist into LDS + stage x in LDS},
// per-image MLP by the 256th finisher (device-scope release), then scale the
// SAME chunk out of LDS (acquire spin on ready[img]). x touches HBM once.
__global__ __launch_bounds__(256, 4) void fused_kernel(
    const float* __restrict__ x,
    const float* __restrict__ W1, const float* __restrict__ b1,
    const float* __restrict__ W2, const float* __restrict__ b2,
    const float* __restrict__ W3, const float* __restrict__ b3,
    const float* __restrict__ W4, const float* __restrict__ b4,
    float* __restrict__ out,
    int* __restrict__ hist, int* __restrict__ done,
    int* __restrict__ ready, float* __restrict__ wval)
{
    __shared__ float stage[2][CHUNK_ELEMS];      // 32 KB
    __shared__ int   lh[NCOPY * HPAD];           // 4.2 KB
    __shared__ float h0[BINS], a1[32], a2[64], a3[BINS];
    __shared__ float wbc;
    __shared__ int   retsh;

    const int t   = threadIdx.x;
    const int g   = blockIdx.x;
    const int cpy = t >> 5;                      // 8 copies, 32 lanes each

    for (int r = 0; r < ROUNDS; ++r) {
        int imgs[2], rets[2];
        imgs[0] = IMGS_PER_ROUND * r + (g >> 8); // 4 images in slot 0
        imgs[1] = imgs[0] + IMGS_PER_SLOT;       // 4 disjoint images in slot 1
        const int cin = g & (CHUNKS_PER_IMG - 1);

        // ---------- A: histogram + LDS staging (both slots) ----------
        #pragma unroll
        for (int s = 0; s < 2; ++s) {
            const int img = imgs[s];
            for (int i = t; i < NCOPY * HPAD; i += 256) lh[i] = 0;
            __syncthreads();

            const f32x4* src = (const f32x4*)(x + (size_t)img * HW_ELEMS
                                                + (size_t)cin * CHUNK_ELEMS);
            f32x4* stg = (f32x4*)stage[s];
            #pragma unroll
            for (int j = 0; j < CHUNK_V4 / 256; ++j) {   // 4 iters
                f32x4 v = src[j * 256 + t];
                stg[j * 256 + t] = v;
                #pragma unroll
                for (int k = 0; k < 4; ++k) {
                    float f = v[k];
                    if (f >= 0.0f && f <= 1.0f) {
                        int b = (int)(f * 128.0f);
                        b = b > 127 ? 127 : b;
                        atomicAdd(&lh[cpy * HPAD + b], 1);
                    }
                }
            }
            __syncthreads();

            if (t < BINS) {
                int ssum = 0;
                #pragma unroll
                for (int c = 0; c < NCOPY; ++c) ssum += lh[c * HPAD + t];
                atomicAdd(&hist[img * BINS + t], ssum);
            }
            __syncthreads();                     // barrier drains vmcnt: adds complete
            if (t == 0) {
                __threadfence();                 // release
                retsh = atomicAdd(&done[img], 1);
            }
            __syncthreads();
            rets[s] = retsh;                     // block-uniform
            __syncthreads();                     // retsh reuse protection
        }

        // ---------- B: 256th finisher runs the MLP for its image ----------
        #pragma unroll
        for (int s = 0; s < 2; ++s) {
            if (rets[s] == CHUNKS_PER_IMG - 1) {
                const int img = imgs[s];
                __threadfence();                 // acquire side
                if (t < BINS) {
                    int hv = __hip_atomic_load(&hist[img * BINS + t],
                                               __ATOMIC_RELAXED, __HIP_MEMORY_SCOPE_AGENT);
                    h0[t] = (float)hv;
                }
                __syncthreads();
                if (t < 32) {
                    float acc = b1[t];
                    #pragma unroll 8
                    for (int i = 0; i < 128; ++i) acc += h0[i] * W1[i * 32 + t];
                    a1[t] = fmaxf(acc, 0.0f);
                }
                __syncthreads();
                if (t < 64) {
                    float acc = b2[t];
                    #pragma unroll 8
                    for (int i = 0; i < 32; ++i) acc += a1[i] * W2[i * 64 + t];
                    a2[t] = fmaxf(acc, 0.0f);
                }
                __syncthreads();
                if (t < 128) {
                    float acc = b3[t];
                    #pragma unroll 8
                    for (int i = 0; i < 64; ++i) acc += a2[i] * W3[i * 128 + t];
                    a3[t] = fmaxf(acc, 0.0f);
                }
                __syncthreads();
                if (t < 64) {
                    float p = a3[t] * W4[t] + a3[t + 64] * W4[t + 64];
                    #pragma unroll
                    for (int off = 32; off > 0; off >>= 1)
                        p += __shfl_down(p, off, 64);
                    if (t == 0) {
                        __hip_atomic_store(&wval[img], p + b4[0],
                                           __ATOMIC_RELAXED, __HIP_MEMORY_SCOPE_AGENT);
                        __hip_atomic_store(&ready[img], 1,
                                           __ATOMIC_RELEASE, __HIP_MEMORY_SCOPE_AGENT);
                    }
                }
                __syncthreads();
            }
        }

        // ---------- C: scale own chunk straight from LDS ----------
        #pragma unroll
        for (int s = 0; s < 2; ++s) {
            const int img = imgs[s];
            if (t == 0) {
                while (__hip_atomic_load(&ready[img], __ATOMIC_ACQUIRE,
                                         __HIP_MEMORY_SCOPE_AGENT) == 0)
                    __builtin_amdgcn_s_sleep(8);
                wbc = __hip_atomic_load(&wval[img], __ATOMIC_RELAXED,
                                        __HIP_MEMORY_SCOPE_AGENT);
            }
            __syncthreads();
            const float w = wbc;
            f32x4* dst = (f32x4*)(out + (size_t)img * HW_ELEMS
                                      + (size_t)cin * CHUNK_ELEMS);
            const f32x4* stg = (const f32x4*)stage[s];
            #pragma unroll
            for (int j = 0; j < CHUNK_V4 / 256; ++j) {
                f32x4 v = stg[j * 256 + t];
                v *= w;
                __builtin_nontemporal_store(v, &dst[j * 256 + t]);
            }
            __syncthreads();                     // wbc/stage reuse protection
        }
    }
}

extern "C" void kernel_launch(void* const* d_in, const int* in_sizes, int n_in,
                              void* d_out, int out_size, void* d_ws, size_t ws_size,
                              hipStream_t stream) {
    const float* x  = (const float*)d_in[0];
    const float* W1 = (const float*)d_in[1];
    const float* b1 = (const float*)d_in[2];
    const float* W2 = (const float*)d_in[3];
    const float* b2 = (const float*)d_in[4];
    const float* W3 = (const float*)d_in[5];
    const float* b3 = (const float*)d_in[6];
    const float* W4 = (const float*)d_in[7];
    const float* b4 = (const float*)d_in[8];
    // d_in[9] = bins (=128), hard-coded

    int*   hist  = (int*)d_ws;                          // 128*128*4 = 64 KB
    int*   done  = hist + N_IMG * BINS;                 // 512 B
    int*   ready = done + N_IMG;                        // 512 B
    float* wval  = (float*)(ready + N_IMG);             // 512 B (flag-guarded, no zeroing)

    // zero hist + done + ready every call (graph-capturable)
    hipMemsetAsync(d_ws, 0, (size_t)(N_IMG * BINS + 2 * N_IMG) * sizeof(int), stream);

    fused_kernel<<<NBLOCKS, 256, 0, stream>>>(x, W1, b1, W2, b2, W3, b3, W4, b4,
                                              (float*)d_out, hist, done, ready, wval);
}

// Round 6
// 586.275 us; speedup vs baseline: 8.6842x; 8.6842x over previous
//
#include <hip/hip_runtime.h>

#define N_IMG 128
#define BINS 128
#define HW_ELEMS (1 << 20)                       // 1024*1024 per image
#define NBLOCKS 1024                             // 4 blocks/CU x 256 CUs (co-resident)
#define CHUNK_ELEMS 4096                         // 16 KB chunk staged in LDS
#define CHUNK_V4 (CHUNK_ELEMS / 4)               // 1024 float4
#define CHUNKS_PER_IMG (HW_ELEMS / CHUNK_ELEMS)  // 256
#define IMGS_PER_SLOT (NBLOCKS / CHUNKS_PER_IMG) // 4
#define IMGS_PER_ROUND (2 * IMGS_PER_SLOT)       // 8
#define ROUNDS (N_IMG / IMGS_PER_ROUND)          // 16
#define NCOPY 8                                  // privatized LDS hist copies (32 lanes each)
#define HPAD 132                                 // 132 % 32 = 4 -> phase-shifted banks
#define FLAG_STRIDE 32                           // 128B per image flag line

typedef float f32x4 __attribute__((ext_vector_type(4)));

// Fence-free device-scope primitives: RMW atomics execute at the coherence
// point (no L2 writeback/invalidate, unlike acquire/release fences which
// flush the per-XCD L2 on MI355X -> the 16x regression in round 5).
__device__ __forceinline__ unsigned rmw_poll(unsigned* p) {
    return __hip_atomic_fetch_or(p, 0u, __ATOMIC_RELAXED, __HIP_MEMORY_SCOPE_AGENT);
}
__device__ __forceinline__ void rmw_store(unsigned* p, unsigned v) {
    __hip_atomic_exchange(p, v, __ATOMIC_RELAXED, __HIP_MEMORY_SCOPE_AGENT);
}
__device__ __forceinline__ int rmw_inc(int* p) {
    return __hip_atomic_fetch_add(p, 1, __ATOMIC_RELAXED, __HIP_MEMORY_SCOPE_AGENT);
}

// One persistent fused kernel: per 16KB chunk -> {hist + stage x in LDS},
// 256th finisher per image runs the MLP inline, then every block scales its
// own chunk straight out of LDS. x crosses HBM exactly once.
__global__ __launch_bounds__(256, 4) void fused_kernel(
    const float* __restrict__ x,
    const float* __restrict__ W1, const float* __restrict__ b1,
    const float* __restrict__ W2, const float* __restrict__ b2,
    const float* __restrict__ W3, const float* __restrict__ b3,
    const float* __restrict__ W4, const float* __restrict__ b4,
    float* __restrict__ out,
    int* __restrict__ hist, int* __restrict__ done,
    unsigned* __restrict__ flags)                // [img*FLAG_STRIDE]=ready, [+1]=w bits
{
    __shared__ float stage[2][CHUNK_ELEMS];      // 32 KB
    __shared__ int   lh[NCOPY * HPAD];           // 4.2 KB
    __shared__ float h0[BINS], a1[32], a2[64], a3[BINS];
    __shared__ float wbc;
    __shared__ int   retsh;

    const int t   = threadIdx.x;
    const int g   = blockIdx.x;
    const int cpy = t >> 5;                      // 8 copies, 32 lanes each

    for (int r = 0; r < ROUNDS; ++r) {
        int imgs[2], rets[2];
        imgs[0] = IMGS_PER_ROUND * r + (g >> 8); // 4 images in slot 0
        imgs[1] = imgs[0] + IMGS_PER_SLOT;       // 4 disjoint images in slot 1
        const int cin = g & (CHUNKS_PER_IMG - 1);

        // ---------- A: histogram + LDS staging (both slots) ----------
        #pragma unroll
        for (int s = 0; s < 2; ++s) {
            const int img = imgs[s];
            for (int i = t; i < NCOPY * HPAD; i += 256) lh[i] = 0;
            __syncthreads();

            const f32x4* src = (const f32x4*)(x + (size_t)img * HW_ELEMS
                                                + (size_t)cin * CHUNK_ELEMS);
            f32x4* stg = (f32x4*)stage[s];
            #pragma unroll
            for (int j = 0; j < CHUNK_V4 / 256; ++j) {   // 4 iters
                f32x4 v = src[j * 256 + t];
                stg[j * 256 + t] = v;
                #pragma unroll
                for (int k = 0; k < 4; ++k) {
                    float f = v[k];
                    if (f >= 0.0f && f <= 1.0f) {
                        int b = (int)(f * 128.0f);
                        b = b > 127 ? 127 : b;
                        atomicAdd(&lh[cpy * HPAD + b], 1);
                    }
                }
            }
            __syncthreads();

            if (t < BINS) {
                int ssum = 0;
                #pragma unroll
                for (int c = 0; c < NCOPY; ++c) ssum += lh[c * HPAD + t];
                atomicAdd(&hist[img * BINS + t], ssum);   // device-scope RMW
            }
            __syncthreads();          // drains vmcnt -> hist adds COMPLETE
            if (t == 0) retsh = rmw_inc(&done[img]);
            __syncthreads();
            rets[s] = retsh;          // block-uniform
            __syncthreads();          // retsh reuse protection
        }

        // ---------- B: 256th finisher runs the MLP for its image ----------
        #pragma unroll
        for (int s = 0; s < 2; ++s) {
            if (rets[s] == CHUNKS_PER_IMG - 1) {
                const int img = imgs[s];
                if (t < BINS) {
                    // all 256 partial adds completed before done hit 255;
                    // relaxed atomic load reads through to coherence point
                    int hv = __hip_atomic_load(&hist[img * BINS + t],
                                               __ATOMIC_RELAXED, __HIP_MEMORY_SCOPE_AGENT);
                    h0[t] = (float)hv;
                }
                __syncthreads();
                if (t < 32) {
                    float acc = b1[t];
                    #pragma unroll 8
                    for (int i = 0; i < 128; ++i) acc += h0[i] * W1[i * 32 + t];
                    a1[t] = fmaxf(acc, 0.0f);
                }
                __syncthreads();
                if (t < 64) {
                    float acc = b2[t];
                    #pragma unroll 8
                    for (int i = 0; i < 32; ++i) acc += a1[i] * W2[i * 64 + t];
                    a2[t] = fmaxf(acc, 0.0f);
                }
                __syncthreads();
                if (t < 128) {
                    float acc = b3[t];
                    #pragma unroll 8
                    for (int i = 0; i < 64; ++i) acc += a2[i] * W3[i * 128 + t];
                    a3[t] = fmaxf(acc, 0.0f);
                }
                __syncthreads();
                if (t < 64) {
                    float p = a3[t] * W4[t] + a3[t + 64] * W4[t + 64];
                    #pragma unroll
                    for (int off = 32; off > 0; off >>= 1)
                        p += __shfl_down(p, off, 64);
                    if (t == 0) {
                        float w = p + b4[0];
                        rmw_store(&flags[img * FLAG_STRIDE + 1], __float_as_uint(w));
                    }
                }
                __syncthreads();      // drains vmcnt -> wval COMPLETE at coherence pt
                if (t == 0) rmw_store(&flags[img * FLAG_STRIDE], 1u);
                __syncthreads();
            }
        }

        // ---------- C: scale own chunk straight from LDS ----------
        #pragma unroll
        for (int s = 0; s < 2; ++s) {
            const int img = imgs[s];
            if (t == 0) {
                while (rmw_poll(&flags[img * FLAG_STRIDE]) == 0u)
                    __builtin_amdgcn_s_sleep(32);        // ~0.85us backoff
                unsigned wb = rmw_poll(&flags[img * FLAG_STRIDE + 1]);
                wbc = __uint_as_float(wb);
            }
            __syncthreads();
            const float w = wbc;
            f32x4* dst = (f32x4*)(out + (size_t)img * HW_ELEMS
                                      + (size_t)cin * CHUNK_ELEMS);
            const f32x4* stg = (const f32x4*)stage[s];
            #pragma unroll
            for (int j = 0; j < CHUNK_V4 / 256; ++j) {
                f32x4 v = stg[j * 256 + t];
                v *= w;
                __builtin_nontemporal_store(v, &dst[j * 256 + t]);
            }
            __syncthreads();          // wbc/stage reuse protection
        }
    }
}

extern "C" void kernel_launch(void* const* d_in, const int* in_sizes, int n_in,
                              void* d_out, int out_size, void* d_ws, size_t ws_size,
                              hipStream_t stream) {
    const float* x  = (const float*)d_in[0];
    const float* W1 = (const float*)d_in[1];
    const float* b1 = (const float*)d_in[2];
    const float* W2 = (const float*)d_in[3];
    const float* b2 = (const float*)d_in[4];
    const float* W3 = (const float*)d_in[5];
    const float* b3 = (const float*)d_in[6];
    const float* W4 = (const float*)d_in[7];
    const float* b4 = (const float*)d_in[8];
    // d_in[9] = bins (=128), hard-coded

    int*      hist  = (int*)d_ws;                       // 64 KB
    int*      done  = hist + N_IMG * BINS;              // 512 B
    unsigned* flags = (unsigned*)(done + N_IMG);        // 128 imgs * 128 B = 16 KB
    // (offset 66048 is 128B-aligned)

    // zero hist + done + flags every call (graph-capturable)
    hipMemsetAsync(d_ws, 0,
                   (size_t)(N_IMG * BINS + N_IMG) * sizeof(int)
                     + (size_t)N_IMG * FLAG_STRIDE * sizeof(unsigned),
                   stream);

    fused_kernel<<<NBLOCKS, 256, 0, stream>>>(x, W1, b1, W2, b2, W3, b3, W4, b4,
                                              (float*)d_out, hist, done, flags);
}